// Round 3
// baseline (159.573 us; speedup 1.0000x reference)
//
#include <hip/hip_runtime.h>

// Problem: B=2048, IN_DIM=1024, HID=512, FEAT=256, all fp32.
//   h_b = relu(x_b @ W_feat + b_feat); f_b = h_b @ W_br_b + b_br_b
//   out[b,c] = sum_{j,i} f1[j] f0[i] W_out[j*256+i, c] + b_out[c]
// Kron trick: W_out viewed as Wr[256,512] (Wr[j][i*2+c] = W_out[j*256+i][c]):
//   t[b,n] = sum_j f1[b,j] Wr[j,n];  out[b,c] = sum_i f0[b,i] t[b,i*2+c] + b_out[c]
// R4: t = h1 @ Wc + bc with Wc = W_br1@Wr (512x512), bc = b_br1@Wr.
// R6 (this round):
//   - fp32-direct A staging REVERTED (measured +3.6us in R5: doubles A-side
//     L2 traffic through the inner loop). prep converts x -> bf16 again.
//   - BK 64 -> 128: halves barrier-drain events per GEMM (m233: fixed
//     stage+drain cost per K-step dominates at small tiles). LDS 2x17.4KB.
//   - kron_reduce: wave-per-row (512 blocks) instead of block-per-row (2048).
// Pipeline: prep -> gemm_h_wc (h + tail-merged Wc) -> gemm_ft (f0||t) -> kron.

typedef __attribute__((ext_vector_type(8))) short bf16x8;  // 8 bf16 = 4 VGPRs
typedef __attribute__((ext_vector_type(4))) float f32x4;
typedef unsigned short u16;

#define LDS_STRIDE 136  // 128 + 8 pad: row stride 272 B -> 2-way bank alias (free, m136)

__device__ __forceinline__ u16 f2bf(float f) {
    unsigned int u = __float_as_uint(f);
    return (u16)((u + 0x7FFFu + ((u >> 16) & 1u)) >> 16);   // RNE
}
__device__ __forceinline__ float bf2f(u16 h) {
    return __uint_as_float(((unsigned int)h) << 16);
}
__device__ __forceinline__ int4 cvt8(const float4& a, const float4& b) {
    int4 r;
    r.x = (int)f2bf(a.x) | ((int)f2bf(a.y) << 16);
    r.y = (int)f2bf(a.z) | ((int)f2bf(a.w) << 16);
    r.z = (int)f2bf(b.x) | ((int)f2bf(b.y) << 16);
    r.w = (int)f2bf(b.z) | ((int)f2bf(b.w) << 16);
    return r;
}

// ---------------- fused prep: all conversions in one launch ----------------
// Ranges (all block-aligned, 256 thr/blk, grid = 5186):
//  R0 [0,       262144): x0 -> bf16, 8 elems/thread
//  R1 [262144,  524288): x1 -> bf16, 8 elems/thread
//  R2 [524288, 1048576): W_feat [1024,512] -> WfT [512][1024] bf16 (transpose)
//  R3 [1048576,1179648): W_br0 [512,256] -> Wb0T [256][512] bf16 (transpose)
//  R4 [1179648,1310720): W_out (viewed Wr[256,512]) -> WrT [512][256] bf16
//  R5 [1310720,1327104): W_br1 [512,256] -> Wb1s bf16 straight copy, 8/thread
//  R6 [1327104,1327616): bc[n] = sum_j b_br1[j] * Wr[j,n]  (fp32)
__global__ __launch_bounds__(256) void prep(
    const float* __restrict__ x0, u16* __restrict__ xb0,
    const float* __restrict__ x1, u16* __restrict__ xb1,
    const float* __restrict__ Wf,  u16* __restrict__ WfT,
    const float* __restrict__ Wb0, u16* __restrict__ Wb0T,
    const float* __restrict__ Wout, u16* __restrict__ WrT,
    const float* __restrict__ Wb1, u16* __restrict__ Wb1s,
    const float* __restrict__ b_br1, float* __restrict__ bc)
{
    int gid = blockIdx.x * 256 + threadIdx.x;
    if (gid < 524288) {                       // R0/R1: x conversion
        const float* s = (gid < 262144) ? x0 : x1;
        u16* d        = (gid < 262144) ? xb0 : xb1;
        int idx = (gid & 262143) * 8;
        float4 a = *(const float4*)&s[idx];
        float4 b = *(const float4*)&s[idx + 4];
        *(int4*)&d[idx] = cvt8(a, b);
    } else if (gid < 1048576) {               // R2: WfT transpose
        int local = gid - 524288;
        int k = local & 1023, n = local >> 10;
        WfT[local] = f2bf(Wf[(size_t)k * 512 + n]);
    } else if (gid < 1179648) {               // R3: Wb0T transpose
        int local = gid - 1048576;
        int k = local & 511, n = local >> 9;
        Wb0T[local] = f2bf(Wb0[(size_t)k * 256 + n]);
    } else if (gid < 1310720) {               // R4: WrT (Wr[j][n] = Wout_flat[j*512+n])
        int local = gid - 1179648;
        int j = local & 255, n = local >> 8;
        WrT[local] = f2bf(Wout[(size_t)j * 512 + n]);
    } else if (gid < 1327104) {               // R5: Wb1 straight bf16 copy
        int idx = (gid - 1310720) * 8;
        float4 a = *(const float4*)&Wb1[idx];
        float4 b = *(const float4*)&Wb1[idx + 4];
        *(int4*)&Wb1s[idx] = cvt8(a, b);
    } else if (gid < 1327616) {               // R6: bc = b_br1 @ Wr (fp32)
        int n = gid - 1327104;
        float acc = 0.0f;
        #pragma unroll 8
        for (int j = 0; j < 256; ++j)
            acc += b_br1[j] * Wout[(size_t)j * 512 + n];
        bc[n] = acc;
    }
}

// ---------------- shared GEMM core, BK = 128 ----------------
// C[bm..bm+64, bn..bn+64] = [relu](A @ W + bias). A: [M,K] bf16 row-major.
// WT: [N,K] bf16 (n-major). 64x64 tile, BK=128, 4 waves each 32x32
// (2x2 frags of 16x16x32). Register-prefetch pipeline: issue tile k+1
// global loads before computing tile k from LDS. K must be a multiple of 128.
__device__ __forceinline__ void gemm_core(
    const u16* __restrict__ A, const u16* __restrict__ WT,
    const float* __restrict__ bias, void* __restrict__ Cv,
    int N, int K, int bm, int bn, int relu, int out_bf16,
    u16* As, u16* Ws)
{
    const int tid  = threadIdx.x;
    const int lane = tid & 63;
    const int wave = tid >> 6;
    const int wr   = wave >> 1;
    const int wc   = wave & 1;
    const int lrow = lane & 15;
    const int quad = lane >> 4;

    // staging: 64 rows x 16 k-chunks (8 bf16) = 1024 chunks; 4 chunks/thread
    const int r0 = tid >> 4;            // rows 0..15 (+16j)
    const int k8 = (tid & 15) * 8;

    const u16* pA[4];
    const u16* pW[4];
    #pragma unroll
    for (int j = 0; j < 4; ++j) {
        pA[j] = A  + (size_t)(bm + r0 + 16 * j) * K + k8;
        pW[j] = WT + (size_t)(bn + r0 + 16 * j) * K + k8;
    }

    f32x4 acc[2][2] = {};

    int4 ra[4], rw[4];
    #pragma unroll
    for (int j = 0; j < 4; ++j) {
        ra[j] = *(const int4*)pA[j];
        rw[j] = *(const int4*)pW[j];
    }
    #pragma unroll
    for (int j = 0; j < 4; ++j) {
        *(int4*)&As[(r0 + 16 * j) * LDS_STRIDE + k8] = ra[j];
        *(int4*)&Ws[(r0 + 16 * j) * LDS_STRIDE + k8] = rw[j];
    }
    __syncthreads();

    for (int kk = 0; kk < K; kk += 128) {
        const int nxt = kk + 128;
        if (nxt < K) {          // prefetch next tile into registers
            #pragma unroll
            for (int j = 0; j < 4; ++j) {
                ra[j] = *(const int4*)(pA[j] + nxt);
                rw[j] = *(const int4*)(pW[j] + nxt);
            }
        }
        #pragma unroll
        for (int ks = 0; ks < 4; ++ks) {
            const int k0 = ks * 32 + quad * 8;
            bf16x8 a0 = *(const bf16x8*)&As[(wr * 32 +      lrow) * LDS_STRIDE + k0];
            bf16x8 a1 = *(const bf16x8*)&As[(wr * 32 + 16 + lrow) * LDS_STRIDE + k0];
            bf16x8 b0 = *(const bf16x8*)&Ws[(wc * 32 +      lrow) * LDS_STRIDE + k0];
            bf16x8 b1 = *(const bf16x8*)&Ws[(wc * 32 + 16 + lrow) * LDS_STRIDE + k0];
            acc[0][0] = __builtin_amdgcn_mfma_f32_16x16x32_bf16(a0, b0, acc[0][0], 0, 0, 0);
            acc[0][1] = __builtin_amdgcn_mfma_f32_16x16x32_bf16(a0, b1, acc[0][1], 0, 0, 0);
            acc[1][0] = __builtin_amdgcn_mfma_f32_16x16x32_bf16(a1, b0, acc[1][0], 0, 0, 0);
            acc[1][1] = __builtin_amdgcn_mfma_f32_16x16x32_bf16(a1, b1, acc[1][1], 0, 0, 0);
        }
        if (nxt < K) {
            __syncthreads();
            #pragma unroll
            for (int j = 0; j < 4; ++j) {
                *(int4*)&As[(r0 + 16 * j) * LDS_STRIDE + k8] = ra[j];
                *(int4*)&Ws[(r0 + 16 * j) * LDS_STRIDE + k8] = rw[j];
            }
            __syncthreads();
        }
    }

    // C/D layout: col=lane&15, row=quad*4+reg (verified m89/m91).
    #pragma unroll
    for (int fm = 0; fm < 2; ++fm) {
        #pragma unroll
        for (int fn = 0; fn < 2; ++fn) {
            const int c = bn + wc * 32 + fn * 16 + lrow;
            const float bv = bias ? bias[c] : 0.0f;
            #pragma unroll
            for (int reg = 0; reg < 4; ++reg) {
                const int r = bm + wr * 32 + fm * 16 + quad * 4 + reg;
                float v = acc[fm][fn][reg] + bv;
                if (relu) v = fmaxf(v, 0.0f);
                if (out_bf16) ((u16*)Cv)[(size_t)r * N + c] = f2bf(v);
                else          ((float*)Cv)[(size_t)r * N + c] = v;
            }
        }
    }
}

// Launch 2: h0/h1 = relu(x@Wf+bf) [2048x512, K=1024] + tail-merged Wc GEMM.
// grid (8, 36, 2). by<32: h-branch z. by>=32: WcT tile-row (by-32)*2+z.
// WcT[n][k] = sum_j WrT[n,j]*Wb1s[k,j] = sum_j Wr[j,n]*Wb1[k,j] = Wc[k,n].
__global__ __launch_bounds__(256) void gemm_h_wc(
    const u16* __restrict__ xb0, const u16* __restrict__ xb1,
    const u16* __restrict__ WfT, const float* __restrict__ b_feat,
    u16* __restrict__ h0, u16* __restrict__ h1,
    const u16* __restrict__ WrT, const u16* __restrict__ Wb1s,
    u16* __restrict__ WcT)
{
    __shared__ __align__(16) u16 As[64 * LDS_STRIDE];
    __shared__ __align__(16) u16 Ws[64 * LDS_STRIDE];
    const int bx = blockIdx.x, by = blockIdx.y, z = blockIdx.z;
    if (by < 32) {
        gemm_core(z ? xb1 : xb0, WfT, b_feat, z ? h1 : h0,
                  512, 1024, by * 64, bx * 64, 1, 1, As, Ws);
    } else {
        const int idx = (by - 32) * 2 + z;          // 8 tile-rows -> M=512
        gemm_core(WrT, Wb1s, nullptr, WcT,
                  512, 256, idx * 64, bx * 64, 0, 1, As, Ws);
    }
}

// Launch 3, flat grid (12, 32): bx<4: f0 = h0@Wb0 + b_br0 [2048x256] bf16
//                               bx>=4: t  = h1@Wc  + bc    [2048x512] fp32
__global__ __launch_bounds__(256) void gemm_ft(
    const u16* __restrict__ h0, const u16* __restrict__ h1,
    const u16* __restrict__ Wb0T, const u16* __restrict__ WcT,
    const float* __restrict__ b_br0, const float* __restrict__ bc,
    u16* __restrict__ f0, float* __restrict__ t)
{
    __shared__ __align__(16) u16 As[64 * LDS_STRIDE];
    __shared__ __align__(16) u16 Ws[64 * LDS_STRIDE];
    const int bx = blockIdx.x;
    if (bx < 4) {
        gemm_core(h0, Wb0T, b_br0, f0,
                  256, 512, blockIdx.y * 64, bx * 64, 0, 1, As, Ws);
    } else {
        gemm_core(h1, WcT, bc, t,
                  512, 512, blockIdx.y * 64, (bx - 4) * 64, 0, 0, As, Ws);
    }
}

// out[b,c] = sum_i f0[b,i] * t[b, i*2+c] + b_out[c].
// One WAVE per row b; 4 rows per 256-thread block; grid = 512.
__global__ __launch_bounds__(256) void kron_reduce(
    const u16* __restrict__ f0, const float* __restrict__ t,
    const float* __restrict__ b_out, float* __restrict__ out)
{
    const int wave = threadIdx.x >> 6;
    const int lane = threadIdx.x & 63;
    const int b = blockIdx.x * 4 + wave;

    const u16*   fr = f0 + (size_t)b * 256;
    const float* tr = t  + (size_t)b * 512;

    float p0 = 0.0f, p1 = 0.0f;
    #pragma unroll
    for (int q = 0; q < 4; ++q) {
        const int i = lane + 64 * q;
        const float  v  = bf2f(fr[i]);
        const float2 tv = ((const float2*)tr)[i];
        p0 += v * tv.x;
        p1 += v * tv.y;
    }
    #pragma unroll
    for (int off = 32; off > 0; off >>= 1) {
        p0 += __shfl_down(p0, off);
        p1 += __shfl_down(p1, off);
    }
    if (lane == 0) {
        float2 o;
        o.x = p0 + b_out[0];
        o.y = p1 + b_out[1];
        ((float2*)out)[b] = o;
    }
}

extern "C" void kernel_launch(void* const* d_in, const int* in_sizes, int n_in,
                              void* d_out, int out_size, void* d_ws, size_t ws_size,
                              hipStream_t stream) {
    const float* x0     = (const float*)d_in[0];
    const float* x1     = (const float*)d_in[1];
    const float* W_feat = (const float*)d_in[2];
    const float* b_feat = (const float*)d_in[3];
    const float* W_br0  = (const float*)d_in[4];
    const float* b_br0  = (const float*)d_in[5];
    const float* W_br1  = (const float*)d_in[6];
    const float* b_br1  = (const float*)d_in[7];
    const float* W_out  = (const float*)d_in[8];
    const float* b_out  = (const float*)d_in[9];
    float* out = (float*)d_out;

    const int B = 2048, IN = 1024, HID = 512, FEAT = 256;

    u16* xb0  = (u16*)d_ws;                  // [2048][1024]
    u16* xb1  = xb0  + (size_t)B * IN;       // [2048][1024]
    u16* WfT  = xb1  + (size_t)B * IN;       // [512][1024]
    u16* Wb0T = WfT  + (size_t)HID * IN;     // [256][512]
    u16* WrT  = Wb0T + (size_t)FEAT * HID;   // [512][256]
    u16* Wb1s = WrT  + (size_t)HID * FEAT;   // [512][256] straight copy
    u16* WcT  = Wb1s + (size_t)HID * FEAT;   // [512][512]
    u16* h0   = WcT  + (size_t)HID * HID;    // [2048][512] bf16
    u16* h1   = h0   + (size_t)B * HID;
    u16* f0   = h1   + (size_t)B * HID;      // [2048][256] bf16
    float* t  = (float*)(f0 + (size_t)B * FEAT);   // [2048][512] fp32
    float* bc = t + (size_t)B * HID;         // [512] fp32
    // total ~19.5 MiB of d_ws

    dim3 blk(256);

    // 1. all conversions + bc in one launch (ranges block-aligned)
    prep<<<dim3(5186), blk, 0, stream>>>(
        x0, xb0, x1, xb1, W_feat, WfT, W_br0, Wb0T, W_out, WrT,
        W_br1, Wb1s, b_br1, bc);

    // 2. h0,h1 (K=1024) + Wc = W_br1@Wr (K=256) tail-merged
    gemm_h_wc<<<dim3(8, 36, 2), blk, 0, stream>>>(
        xb0, xb1, WfT, b_feat, h0, h1, WrT, Wb1s, WcT);

    // 3. f0 = h0@Wb0+b_br0 (bf16) || t = h1@Wc+bc (fp32), flat grid
    gemm_ft<<<dim3(12, 32), blk, 0, stream>>>(
        h0, h1, Wb0T, WcT, b_br0, bc, f0, t);

    // 4. out[b,c] = sum_i f0[b,i]*t[b,i*2+c] + b_out[c]; wave-per-row
    kron_reduce<<<dim3(512), blk, 0, stream>>>(f0, t, b_out, out);
}

// Round 4
// 115.877 us; speedup vs baseline: 1.3771x; 1.3771x over previous
//
#include <hip/hip_runtime.h>

// Problem: B=2048, IN_DIM=1024, HID=512, FEAT=256, all fp32.
//   h_b = relu(x_b @ W_feat + b_feat); f_b = h_b @ W_br_b + b_br_b
//   out[b,c] = sum_{j,i} f1[j] f0[i] W_out[j*256+i, c] + b_out[c]
// Kron trick: W_out viewed as Wr[256,512] (Wr[j][i*2+c] = W_out[j*256+i][c]):
//   t[b,n] = sum_j f1[b,j] Wr[j,n];  out[b,c] = sum_i f0[b,i] t[b,i*2+c] + b_out[c]
// Structural fusion (R4, measured 120.9us): t = h1@Wc + bc, Wc = W_br1@Wr.
// R7 (this round): REVERT R6's BK=128 — rocprof showed gemm_h_wc at 49us,
//   MfmaUtil 3%, WRITE_SIZE 90MB on a 4.5MB-write kernel: the int4 prefetch
//   ARRAYS spilled to scratch (rule #20; VGPR_Count=60 confirms). Back to
//   BK=64 with NAMED scalar prefetch regs (the 119-121us structure).
//   Kept from R6 (safe, uninvolved in regression): wave-per-row kron_reduce
//   (512 blocks), flat gemm_ft grid (12,32).
// Pipeline: prep -> gemm_h_wc (h + tail-merged Wc) -> gemm_ft (f0||t) -> kron.

typedef __attribute__((ext_vector_type(8))) short bf16x8;  // 8 bf16 = 4 VGPRs
typedef __attribute__((ext_vector_type(4))) float f32x4;
typedef unsigned short u16;

#define LDS_STRIDE 72   // 64 + 8 pad: row stride 144 B -> 2-way bank alias (free, m136)

__device__ __forceinline__ u16 f2bf(float f) {
    unsigned int u = __float_as_uint(f);
    return (u16)((u + 0x7FFFu + ((u >> 16) & 1u)) >> 16);   // RNE
}
__device__ __forceinline__ float bf2f(u16 h) {
    return __uint_as_float(((unsigned int)h) << 16);
}
__device__ __forceinline__ int4 cvt8(const float4& a, const float4& b) {
    int4 r;
    r.x = (int)f2bf(a.x) | ((int)f2bf(a.y) << 16);
    r.y = (int)f2bf(a.z) | ((int)f2bf(a.w) << 16);
    r.z = (int)f2bf(b.x) | ((int)f2bf(b.y) << 16);
    r.w = (int)f2bf(b.z) | ((int)f2bf(b.w) << 16);
    return r;
}

// ---------------- fused prep: all conversions in one launch ----------------
// Ranges (all block-aligned, 256 thr/blk, grid = 5186):
//  R0 [0,       262144): x0 -> bf16, 8 elems/thread
//  R1 [262144,  524288): x1 -> bf16, 8 elems/thread
//  R2 [524288, 1048576): W_feat [1024,512] -> WfT [512][1024] bf16 (transpose)
//  R3 [1048576,1179648): W_br0 [512,256] -> Wb0T [256][512] bf16 (transpose)
//  R4 [1179648,1310720): W_out (viewed Wr[256,512]) -> WrT [512][256] bf16
//  R5 [1310720,1327104): W_br1 [512,256] -> Wb1s bf16 straight copy, 8/thread
//  R6 [1327104,1327616): bc[n] = sum_j b_br1[j] * Wr[j,n]  (fp32)
__global__ __launch_bounds__(256) void prep(
    const float* __restrict__ x0, u16* __restrict__ xb0,
    const float* __restrict__ x1, u16* __restrict__ xb1,
    const float* __restrict__ Wf,  u16* __restrict__ WfT,
    const float* __restrict__ Wb0, u16* __restrict__ Wb0T,
    const float* __restrict__ Wout, u16* __restrict__ WrT,
    const float* __restrict__ Wb1, u16* __restrict__ Wb1s,
    const float* __restrict__ b_br1, float* __restrict__ bc)
{
    int gid = blockIdx.x * 256 + threadIdx.x;
    if (gid < 524288) {                       // R0/R1: x conversion
        const float* s = (gid < 262144) ? x0 : x1;
        u16* d        = (gid < 262144) ? xb0 : xb1;
        int idx = (gid & 262143) * 8;
        float4 a = *(const float4*)&s[idx];
        float4 b = *(const float4*)&s[idx + 4];
        *(int4*)&d[idx] = cvt8(a, b);
    } else if (gid < 1048576) {               // R2: WfT transpose
        int local = gid - 524288;
        int k = local & 1023, n = local >> 10;
        WfT[local] = f2bf(Wf[(size_t)k * 512 + n]);
    } else if (gid < 1179648) {               // R3: Wb0T transpose
        int local = gid - 1048576;
        int k = local & 511, n = local >> 9;
        Wb0T[local] = f2bf(Wb0[(size_t)k * 256 + n]);
    } else if (gid < 1310720) {               // R4: WrT (Wr[j][n] = Wout_flat[j*512+n])
        int local = gid - 1179648;
        int j = local & 255, n = local >> 8;
        WrT[local] = f2bf(Wout[(size_t)j * 512 + n]);
    } else if (gid < 1327104) {               // R5: Wb1 straight bf16 copy
        int idx = (gid - 1310720) * 8;
        float4 a = *(const float4*)&Wb1[idx];
        float4 b = *(const float4*)&Wb1[idx + 4];
        *(int4*)&Wb1s[idx] = cvt8(a, b);
    } else if (gid < 1327616) {               // R6: bc = b_br1 @ Wr (fp32)
        int n = gid - 1327104;
        float acc = 0.0f;
        #pragma unroll 8
        for (int j = 0; j < 256; ++j)
            acc += b_br1[j] * Wout[(size_t)j * 512 + n];
        bc[n] = acc;
    }
}

// ---------------- shared GEMM core, BK = 64 ----------------
// C[bm..bm+64, bn..bn+64] = [relu](A @ W + bias). A: [M,K] bf16 row-major.
// WT: [N,K] bf16 (n-major). 64x64 tile, BK=64, 4 waves each 32x32
// (2x2 frags of 16x16x32). Register-prefetch pipeline with NAMED scalar
// registers (int4 ra0/ra1/rw0/rw1 — arrays here spill to scratch, rule #20;
// R6 measured that at 3x cost). Issue tile k+1 loads before computing tile k.
__device__ __forceinline__ void gemm_core(
    const u16* __restrict__ A, const u16* __restrict__ WT,
    const float* __restrict__ bias, void* __restrict__ Cv,
    int N, int K, int bm, int bn, int relu, int out_bf16,
    u16* As, u16* Ws)
{
    const int tid  = threadIdx.x;
    const int lane = tid & 63;
    const int wave = tid >> 6;
    const int wr   = wave >> 1;
    const int wc   = wave & 1;
    const int lrow = lane & 15;
    const int quad = lane >> 4;

    // staging: 512 chunks of 8 bf16 per tile; thread covers rows r0 and r1
    const int r0 = tid >> 3;            // rows 0..31
    const int r1 = r0 + 32;             // rows 32..63
    const int k8 = (tid & 7) * 8;

    const u16* pA0 = A  + (size_t)(bm + r0) * K + k8;
    const u16* pA1 = A  + (size_t)(bm + r1) * K + k8;
    const u16* pW0 = WT + (size_t)(bn + r0) * K + k8;
    const u16* pW1 = WT + (size_t)(bn + r1) * K + k8;

    f32x4 acc[2][2] = {};

    int4 ra0 = *(const int4*)pA0;
    int4 ra1 = *(const int4*)pA1;
    int4 rw0 = *(const int4*)pW0;
    int4 rw1 = *(const int4*)pW1;
    *(int4*)&As[r0 * LDS_STRIDE + k8] = ra0;
    *(int4*)&As[r1 * LDS_STRIDE + k8] = ra1;
    *(int4*)&Ws[r0 * LDS_STRIDE + k8] = rw0;
    *(int4*)&Ws[r1 * LDS_STRIDE + k8] = rw1;
    __syncthreads();

    for (int kk = 0; kk < K; kk += 64) {
        const int nxt = kk + 64;
        if (nxt < K) {          // prefetch next tile into registers
            ra0 = *(const int4*)(pA0 + nxt);
            ra1 = *(const int4*)(pA1 + nxt);
            rw0 = *(const int4*)(pW0 + nxt);
            rw1 = *(const int4*)(pW1 + nxt);
        }
        #pragma unroll
        for (int ks = 0; ks < 2; ++ks) {
            const int k0 = ks * 32 + quad * 8;
            bf16x8 a0 = *(const bf16x8*)&As[(wr * 32 +      lrow) * LDS_STRIDE + k0];
            bf16x8 a1 = *(const bf16x8*)&As[(wr * 32 + 16 + lrow) * LDS_STRIDE + k0];
            bf16x8 b0 = *(const bf16x8*)&Ws[(wc * 32 +      lrow) * LDS_STRIDE + k0];
            bf16x8 b1 = *(const bf16x8*)&Ws[(wc * 32 + 16 + lrow) * LDS_STRIDE + k0];
            acc[0][0] = __builtin_amdgcn_mfma_f32_16x16x32_bf16(a0, b0, acc[0][0], 0, 0, 0);
            acc[0][1] = __builtin_amdgcn_mfma_f32_16x16x32_bf16(a0, b1, acc[0][1], 0, 0, 0);
            acc[1][0] = __builtin_amdgcn_mfma_f32_16x16x32_bf16(a1, b0, acc[1][0], 0, 0, 0);
            acc[1][1] = __builtin_amdgcn_mfma_f32_16x16x32_bf16(a1, b1, acc[1][1], 0, 0, 0);
        }
        if (nxt < K) {
            __syncthreads();
            *(int4*)&As[r0 * LDS_STRIDE + k8] = ra0;
            *(int4*)&As[r1 * LDS_STRIDE + k8] = ra1;
            *(int4*)&Ws[r0 * LDS_STRIDE + k8] = rw0;
            *(int4*)&Ws[r1 * LDS_STRIDE + k8] = rw1;
            __syncthreads();
        }
    }

    // C/D layout: col=lane&15, row=quad*4+reg (verified m89/m91).
    #pragma unroll
    for (int fm = 0; fm < 2; ++fm) {
        #pragma unroll
        for (int fn = 0; fn < 2; ++fn) {
            const int c = bn + wc * 32 + fn * 16 + lrow;
            const float bv = bias ? bias[c] : 0.0f;
            #pragma unroll
            for (int reg = 0; reg < 4; ++reg) {
                const int r = bm + wr * 32 + fm * 16 + quad * 4 + reg;
                float v = acc[fm][fn][reg] + bv;
                if (relu) v = fmaxf(v, 0.0f);
                if (out_bf16) ((u16*)Cv)[(size_t)r * N + c] = f2bf(v);
                else          ((float*)Cv)[(size_t)r * N + c] = v;
            }
        }
    }
}

// Launch 2: h0/h1 = relu(x@Wf+bf) [2048x512, K=1024] + tail-merged Wc GEMM.
// grid (8, 36, 2). by<32: h-branch z. by>=32: WcT tile-row (by-32)*2+z.
// WcT[n][k] = sum_j WrT[n,j]*Wb1s[k,j] = sum_j Wr[j,n]*Wb1[k,j] = Wc[k,n].
__global__ __launch_bounds__(256) void gemm_h_wc(
    const u16* __restrict__ xb0, const u16* __restrict__ xb1,
    const u16* __restrict__ WfT, const float* __restrict__ b_feat,
    u16* __restrict__ h0, u16* __restrict__ h1,
    const u16* __restrict__ WrT, const u16* __restrict__ Wb1s,
    u16* __restrict__ WcT)
{
    __shared__ __align__(16) u16 As[64 * LDS_STRIDE];
    __shared__ __align__(16) u16 Ws[64 * LDS_STRIDE];
    const int bx = blockIdx.x, by = blockIdx.y, z = blockIdx.z;
    if (by < 32) {
        gemm_core(z ? xb1 : xb0, WfT, b_feat, z ? h1 : h0,
                  512, 1024, by * 64, bx * 64, 1, 1, As, Ws);
    } else {
        const int idx = (by - 32) * 2 + z;          // 8 tile-rows -> M=512
        gemm_core(WrT, Wb1s, nullptr, WcT,
                  512, 256, idx * 64, bx * 64, 0, 1, As, Ws);
    }
}

// Launch 3, flat grid (12, 32): bx<4: f0 = h0@Wb0 + b_br0 [2048x256] bf16
//                               bx>=4: t  = h1@Wc  + bc    [2048x512] fp32
__global__ __launch_bounds__(256) void gemm_ft(
    const u16* __restrict__ h0, const u16* __restrict__ h1,
    const u16* __restrict__ Wb0T, const u16* __restrict__ WcT,
    const float* __restrict__ b_br0, const float* __restrict__ bc,
    u16* __restrict__ f0, float* __restrict__ t)
{
    __shared__ __align__(16) u16 As[64 * LDS_STRIDE];
    __shared__ __align__(16) u16 Ws[64 * LDS_STRIDE];
    const int bx = blockIdx.x;
    if (bx < 4) {
        gemm_core(h0, Wb0T, b_br0, f0,
                  256, 512, blockIdx.y * 64, bx * 64, 0, 1, As, Ws);
    } else {
        gemm_core(h1, WcT, bc, t,
                  512, 512, blockIdx.y * 64, (bx - 4) * 64, 0, 0, As, Ws);
    }
}

// out[b,c] = sum_i f0[b,i] * t[b, i*2+c] + b_out[c].
// One WAVE per row b; 4 rows per 256-thread block; grid = 512.
__global__ __launch_bounds__(256) void kron_reduce(
    const u16* __restrict__ f0, const float* __restrict__ t,
    const float* __restrict__ b_out, float* __restrict__ out)
{
    const int wave = threadIdx.x >> 6;
    const int lane = threadIdx.x & 63;
    const int b = blockIdx.x * 4 + wave;

    const u16*   fr = f0 + (size_t)b * 256;
    const float* tr = t  + (size_t)b * 512;

    float p0 = 0.0f, p1 = 0.0f;
    #pragma unroll
    for (int q = 0; q < 4; ++q) {
        const int i = lane + 64 * q;
        const float  v  = bf2f(fr[i]);
        const float2 tv = ((const float2*)tr)[i];
        p0 += v * tv.x;
        p1 += v * tv.y;
    }
    #pragma unroll
    for (int off = 32; off > 0; off >>= 1) {
        p0 += __shfl_down(p0, off);
        p1 += __shfl_down(p1, off);
    }
    if (lane == 0) {
        float2 o;
        o.x = p0 + b_out[0];
        o.y = p1 + b_out[1];
        ((float2*)out)[b] = o;
    }
}

extern "C" void kernel_launch(void* const* d_in, const int* in_sizes, int n_in,
                              void* d_out, int out_size, void* d_ws, size_t ws_size,
                              hipStream_t stream) {
    const float* x0     = (const float*)d_in[0];
    const float* x1     = (const float*)d_in[1];
    const float* W_feat = (const float*)d_in[2];
    const float* b_feat = (const float*)d_in[3];
    const float* W_br0  = (const float*)d_in[4];
    const float* b_br0  = (const float*)d_in[5];
    const float* W_br1  = (const float*)d_in[6];
    const float* b_br1  = (const float*)d_in[7];
    const float* W_out  = (const float*)d_in[8];
    const float* b_out  = (const float*)d_in[9];
    float* out = (float*)d_out;

    const int B = 2048, IN = 1024, HID = 512, FEAT = 256;

    u16* xb0  = (u16*)d_ws;                  // [2048][1024]
    u16* xb1  = xb0  + (size_t)B * IN;       // [2048][1024]
    u16* WfT  = xb1  + (size_t)B * IN;       // [512][1024]
    u16* Wb0T = WfT  + (size_t)HID * IN;     // [256][512]
    u16* WrT  = Wb0T + (size_t)FEAT * HID;   // [512][256]
    u16* Wb1s = WrT  + (size_t)HID * FEAT;   // [512][256] straight copy
    u16* WcT  = Wb1s + (size_t)HID * FEAT;   // [512][512]
    u16* h0   = WcT  + (size_t)HID * HID;    // [2048][512] bf16
    u16* h1   = h0   + (size_t)B * HID;
    u16* f0   = h1   + (size_t)B * HID;      // [2048][256] bf16
    float* t  = (float*)(f0 + (size_t)B * FEAT);   // [2048][512] fp32
    float* bc = t + (size_t)B * HID;         // [512] fp32
    // total ~19.5 MiB of d_ws

    dim3 blk(256);

    // 1. all conversions + bc in one launch (ranges block-aligned)
    prep<<<dim3(5186), blk, 0, stream>>>(
        x0, xb0, x1, xb1, W_feat, WfT, W_br0, Wb0T, W_out, WrT,
        W_br1, Wb1s, b_br1, bc);

    // 2. h0,h1 (K=1024) + Wc = W_br1@Wr (K=256) tail-merged
    gemm_h_wc<<<dim3(8, 36, 2), blk, 0, stream>>>(
        xb0, xb1, WfT, b_feat, h0, h1, WrT, Wb1s, WcT);

    // 3. f0 = h0@Wb0+b_br0 (bf16) || t = h1@Wc+bc (fp32), flat grid
    gemm_ft<<<dim3(12, 32), blk, 0, stream>>>(
        h0, h1, Wb0T, WcT, b_br0, bc, f0, t);

    // 4. out[b,c] = sum_i f0[b,i]*t[b,i*2+c] + b_out[c]; wave-per-row
    kron_reduce<<<dim3(512), blk, 0, stream>>>(f0, t, b_out, out);
}